// Round 2
// baseline (369.702 us; speedup 1.0000x reference)
//
#include <hip/hip_runtime.h>
#include <math.h>

// Problem shape (fixed): B=2, C=256, H=W=64 -> N=4096, d=64, K=32, M=256, topk=8
#define QOFF 32
#define KOFF 96
#define VOFF 160

// ============================================================================
// Kernel A: fused projection GEMM.  Y[b][n][0..415] = {sem_logits(32), q(64),
// k(64), v(256)} ; Y row-major position rows of 416 floats.
// Tile 64oc x 64n, K=256 in chunks of 16, thread tile 4x4.
// ============================================================================
__global__ __launch_bounds__(256) void proj_kernel(
    const float* __restrict__ x,
    const float* __restrict__ sem_w, const float* __restrict__ sem_b,
    const float* __restrict__ q_w, const float* __restrict__ k_w,
    const float* __restrict__ v_w, float* __restrict__ Y)
{
    const int t = threadIdx.x;
    const int n0 = blockIdx.x * 64;
    const int oc0 = blockIdx.y * 64;
    const int b = blockIdx.z;
    const int ty = t >> 4, tx = t & 15;

    __shared__ float As[16][68];   // [c_in_chunk][oc_local], padded
    __shared__ float Bs[16][64];   // [c_in_chunk][n_local]

    float acc[4][4];
#pragma unroll
    for (int i = 0; i < 4; i++)
#pragma unroll
        for (int j = 0; j < 4; j++) acc[i][j] = 0.f;

    const int oc_l = t >> 2;        // 0..63
    const int cp = t & 3;           // 0..3
    const int oc_g = oc0 + oc_l;
    const float* wrow = nullptr;
    if (oc_g < 32) wrow = sem_w + oc_g * 256;
    else if (oc_g < 96) wrow = q_w + (oc_g - 32) * 256;
    else if (oc_g < 160) wrow = k_w + (oc_g - 96) * 256;
    else if (oc_g < 416) wrow = v_w + (oc_g - 160) * 256;

    const int bk = t >> 4;          // 0..15
    const int bn = (t & 15) << 2;   // 0..60

    for (int c0 = 0; c0 < 256; c0 += 16) {
        __syncthreads();
        float4 w4 = make_float4(0.f, 0.f, 0.f, 0.f);
        if (wrow) w4 = *(const float4*)(wrow + c0 + (cp << 2));
        As[(cp << 2) + 0][oc_l] = w4.x;
        As[(cp << 2) + 1][oc_l] = w4.y;
        As[(cp << 2) + 2][oc_l] = w4.z;
        As[(cp << 2) + 3][oc_l] = w4.w;
        *(float4*)&Bs[bk][bn] =
            *(const float4*)(x + ((size_t)(b * 256 + c0 + bk)) * 4096 + n0 + bn);
        __syncthreads();
#pragma unroll
        for (int kk = 0; kk < 16; kk++) {
            float4 a4 = *(float4*)&As[kk][ty << 2];
            float4 b4 = *(float4*)&Bs[kk][tx << 2];
            acc[0][0] += a4.x * b4.x; acc[0][1] += a4.x * b4.y;
            acc[0][2] += a4.x * b4.z; acc[0][3] += a4.x * b4.w;
            acc[1][0] += a4.y * b4.x; acc[1][1] += a4.y * b4.y;
            acc[1][2] += a4.y * b4.z; acc[1][3] += a4.y * b4.w;
            acc[2][0] += a4.z * b4.x; acc[2][1] += a4.z * b4.y;
            acc[2][2] += a4.z * b4.z; acc[2][3] += a4.z * b4.w;
            acc[3][0] += a4.w * b4.x; acc[3][1] += a4.w * b4.y;
            acc[3][2] += a4.w * b4.z; acc[3][3] += a4.w * b4.w;
        }
    }

    if (oc0 + (ty << 2) < 416) {
        float bias[4];
#pragma unroll
        for (int i = 0; i < 4; i++) {
            int oc = oc0 + (ty << 2) + i;
            bias[i] = (oc < 32) ? sem_b[oc] : 0.f;
        }
#pragma unroll
        for (int j = 0; j < 4; j++) {
            int n = n0 + (tx << 2) + j;
            float4 o4 = make_float4(acc[0][j] + bias[0], acc[1][j] + bias[1],
                                    acc[2][j] + bias[2], acc[3][j] + bias[3]);
            *(float4*)(Y + ((size_t)(b * 4096 + n)) * 416 + oc0 + (ty << 2)) = o4;
        }
    }
}

// ============================================================================
// Kernel B: per-position softmax over the 32 sem logits (in place) + argmax
// (first-max tie-break, matches jnp.argmax).
// ============================================================================
__global__ __launch_bounds__(256) void semsoft_kernel(float* __restrict__ Y,
                                                      int* __restrict__ hr)
{
    const int g = blockIdx.x * 256 + threadIdx.x;   // 0..8191 (= b*4096+n)
    float* row = Y + (size_t)g * 416;
    float v[32];
#pragma unroll
    for (int i = 0; i < 8; i++) *(float4*)&v[i * 4] = *(float4*)&row[i * 4];
    float mx = v[0]; int am = 0;
#pragma unroll
    for (int kk = 1; kk < 32; kk++) if (v[kk] > mx) { mx = v[kk]; am = kk; }
    float s = 0.f;
#pragma unroll
    for (int kk = 0; kk < 32; kk++) { v[kk] = expf(v[kk] - mx); s += v[kk]; }
    const float inv = 1.f / s;
#pragma unroll
    for (int kk = 0; kk < 32; kk++) v[kk] *= inv;
#pragma unroll
    for (int i = 0; i < 8; i++) *(float4*)&row[i * 4] = *(float4*)&v[i * 4];
    hr[g] = am;
}

// ============================================================================
// Kernel C: region_k / region_v chunk partials.
// P[b][chunk][k][dd] : dd 0..63 -> region_k, dd 64..319 -> region_v.
// One block per (chunk of 128 positions, b).
// ============================================================================
__global__ __launch_bounds__(256) void region_partial_kernel(
    const float* __restrict__ Y, float* __restrict__ P)
{
    const int ch = blockIdx.x, b = blockIdx.y;
    const int t = threadIdx.x;
    __shared__ float row_s[416];
    const int kset = t & 7;    // owns k = kset*4 + i
    const int dds = t >> 3;    // owns dd = dds*10 + j
    float acc[4][10];
#pragma unroll
    for (int i = 0; i < 4; i++)
#pragma unroll
        for (int j = 0; j < 10; j++) acc[i][j] = 0.f;
    const size_t gbase = (size_t)(b * 4096 + ch * 128);
    for (int nn = 0; nn < 128; nn++) {
        __syncthreads();
        const float* row = Y + (gbase + nn) * 416;
        if (t < 208) { row_s[t] = row[t]; row_s[t + 208] = row[t + 208]; }
        __syncthreads();
        float sv[4], kv[10];
#pragma unroll
        for (int i = 0; i < 4; i++) sv[i] = row_s[(kset << 2) + i];
#pragma unroll
        for (int j = 0; j < 10; j++) kv[j] = row_s[96 + dds * 10 + j];
#pragma unroll
        for (int i = 0; i < 4; i++)
#pragma unroll
            for (int j = 0; j < 10; j++) acc[i][j] += sv[i] * kv[j];
    }
    float* Pb = P + ((size_t)(b * 32 + ch)) * 10240;
#pragma unroll
    for (int i = 0; i < 4; i++)
#pragma unroll
        for (int j = 0; j < 10; j++)
            Pb[((kset << 2) + i) * 320 + dds * 10 + j] = acc[i][j];
}

__global__ __launch_bounds__(256) void region_reduce_kernel(
    const float* __restrict__ P, float* __restrict__ region)
{
    const int idx = blockIdx.x * 256 + threadIdx.x;
    if (idx >= 2 * 10240) return;
    const int b = idx / 10240, rem = idx - b * 10240;
    float s = 0.f;
    for (int ch = 0; ch < 32; ch++)
        s += P[((size_t)(b * 32 + ch)) * 10240 + rem];
    region[(size_t)b * 10240 + rem] = s;
}

// ============================================================================
// Kernel D: top-256 indices of sem[b][k][:] over N=4096 (set semantics;
// value-desc with index-asc tie-break at the threshold boundary).
// Binary search on order-preserving uint mapping, then gather.
// ============================================================================
__global__ __launch_bounds__(256) void topk_sem_kernel(
    const float* __restrict__ Y, int* __restrict__ ti)
{
    const int kreg = blockIdx.x, b = blockIdx.y;
    const int t = threadIdx.x;
    __shared__ int wpart[4];
    __shared__ int sh_eq[256];
    __shared__ int ctr;

    unsigned int uv[16];
    const int nbase = t * 16;   // blocked partition -> index-ordered scan
#pragma unroll
    for (int i = 0; i < 16; i++) {
        float v = Y[((size_t)(b * 4096 + nbase + i)) * 416 + kreg];
        unsigned int u = __float_as_uint(v);
        uv[i] = (u & 0x80000000u) ? ~u : (u | 0x80000000u);
    }
    unsigned long long lo = 0ull, hi = 0xFFFFFFFFull;
    while (lo < hi) {
        const unsigned int mid = (unsigned int)((lo + hi + 1ull) >> 1);
        int c = 0;
#pragma unroll
        for (int i = 0; i < 16; i++) c += (uv[i] >= mid) ? 1 : 0;
#pragma unroll
        for (int off = 1; off < 64; off <<= 1) c += __shfl_xor(c, off);
        __syncthreads();
        if ((t & 63) == 0) wpart[t >> 6] = c;
        __syncthreads();
        const int tot = wpart[0] + wpart[1] + wpart[2] + wpart[3];
        if (tot >= 256) lo = mid; else hi = (unsigned long long)mid - 1ull;
    }
    const unsigned int T = (unsigned int)lo;
    int cgt = 0, ceq = 0;
#pragma unroll
    for (int i = 0; i < 16; i++) { cgt += (uv[i] > T) ? 1 : 0; ceq += (uv[i] == T) ? 1 : 0; }
    int cg = cgt;
#pragma unroll
    for (int off = 1; off < 64; off <<= 1) cg += __shfl_xor(cg, off);
    __syncthreads();
    if ((t & 63) == 0) wpart[t >> 6] = cg;
    sh_eq[t] = ceq;
    if (t == 0) ctr = 0;
    __syncthreads();
    const int c1 = wpart[0] + wpart[1] + wpart[2] + wpart[3];
    int eqbase = 0;
    for (int i = 0; i < t; i++) eqbase += sh_eq[i];
    int* outp = ti + ((size_t)(b * 32 + kreg)) * 256;
    int seen = 0;
#pragma unroll
    for (int i = 0; i < 16; i++) {
        if (uv[i] > T) {
            int pos = atomicAdd(&ctr, 1);
            outp[pos] = nbase + i;
        } else if (uv[i] == T) {
            int r = eqbase + seen; seen++;
            if (c1 + r < 256) outp[c1 + r] = nbase + i;
        }
    }
}

// ============================================================================
// Kernel E: sparse branch. One wave per position: sims over region pool of
// 256 keys, iterative top-8 (lowest-index tie), softmax, weighted V gather.
// ============================================================================
__global__ __launch_bounds__(256) void sparse_attn_kernel(
    const float* __restrict__ Y, const int* __restrict__ hr,
    const int* __restrict__ ti, float* __restrict__ sp)
{
    const int t = threadIdx.x;
    const int wid = t >> 6, lane = t & 63;
    const int g = blockIdx.x * 4 + wid;     // b*4096 + n
    const int b = g >> 12;
    __shared__ float q_s[4][64];
    __shared__ int pool_s[4][256];
    __shared__ float sims_s[4][256];

    q_s[wid][lane] = Y[(size_t)g * 416 + QOFF + lane];
    const int region = hr[g];
    *(int4*)&pool_s[wid][lane << 2] =
        *(const int4*)(ti + ((size_t)(b * 32 + region)) * 256 + (lane << 2));
    __syncthreads();

    float4 qr[16];
    {
        const float4* q4 = (const float4*)q_s[wid];
#pragma unroll
        for (int j = 0; j < 16; j++) qr[j] = q4[j];
    }
    const float inv_scale = 1.0f / (8.0f + 1e-6f);
#pragma unroll
    for (int r = 0; r < 4; r++) {
        const int m = (r << 6) + lane;
        const int kidx = pool_s[wid][m];
        const float4* kr = (const float4*)(Y + ((size_t)(b * 4096 + kidx)) * 416 + KOFF);
        float s = 0.f;
#pragma unroll
        for (int j = 0; j < 16; j++) {
            float4 kv = kr[j];
            s += qr[j].x * kv.x + qr[j].y * kv.y + qr[j].z * kv.z + qr[j].w * kv.w;
        }
        sims_s[wid][m] = s * inv_scale;
    }
    __syncthreads();

    float topv[8]; int topm[8];
#pragma unroll
    for (int sel = 0; sel < 8; sel++) {
        float4 sv = *(float4*)&sims_s[wid][lane << 2];
        float bv = sv.x; int bm = (lane << 2);
        if (sv.y > bv) { bv = sv.y; bm = (lane << 2) + 1; }
        if (sv.z > bv) { bv = sv.z; bm = (lane << 2) + 2; }
        if (sv.w > bv) { bv = sv.w; bm = (lane << 2) + 3; }
#pragma unroll
        for (int off = 1; off < 64; off <<= 1) {
            float ov = __shfl_xor(bv, off);
            int om = __shfl_xor(bm, off);
            if (ov > bv || (ov == bv && om < bm)) { bv = ov; bm = om; }
        }
        topv[sel] = bv; topm[sel] = bm;
        if (lane == (bm >> 2)) sims_s[wid][bm] = -3e38f;
        __syncthreads();
    }

    const float mx = topv[0];
    float att[8]; float esum = 0.f;
#pragma unroll
    for (int j = 0; j < 8; j++) { att[j] = expf(topv[j] - mx); esum += att[j]; }
    const float inv = 1.f / esum;

    float4 acc = make_float4(0.f, 0.f, 0.f, 0.f);
#pragma unroll
    for (int j = 0; j < 8; j++) {
        const int actual = pool_s[wid][topm[j]];
        const float4 vv = *(const float4*)(
            Y + ((size_t)(b * 4096 + actual)) * 416 + VOFF + (lane << 2));
        const float w = att[j] * inv;
        acc.x += w * vv.x; acc.y += w * vv.y; acc.z += w * vv.z; acc.w += w * vv.w;
    }
    *(float4*)(sp + (size_t)g * 256 + (lane << 2)) = acc;
}

// ============================================================================
// Kernel F: dense region-attention branch per position + combine with sparse
// (in place over sp). One wave per position; region_k/v staged in LDS.
// ============================================================================
__global__ __launch_bounds__(256) void combine_kernel(
    const float* __restrict__ Y, const float* __restrict__ region,
    const float* __restrict__ alpha, float* __restrict__ sp)
{
    const int t = threadIdx.x;
    const int wid = t >> 6, lane = t & 63;
    const int g = blockIdx.x * 4 + wid;
    const int b = g >> 12;
    __shared__ float rk_s[32][65];
    __shared__ float rv_s[32][256];
    __shared__ float a_s[4][32];
    __shared__ float q_s[4][64];

    const float* reg = region + (size_t)b * 10240;
    for (int idx = t; idx < 10240; idx += 256) {
        const int kk = idx / 320, dd = idx - kk * 320;
        const float v = reg[idx];
        if (dd < 64) rk_s[kk][dd] = v; else rv_s[kk][dd - 64] = v;
    }
    q_s[wid][lane] = Y[(size_t)g * 416 + QOFF + lane];
    __syncthreads();

    const int kk = lane & 31, half = lane >> 5;
    float part = 0.f;
    {
        const float* qsw = q_s[wid] + (half << 5);
        const float* rkr = &rk_s[kk][half << 5];
#pragma unroll
        for (int j = 0; j < 32; j++) part += qsw[j] * rkr[j];
    }
    part += __shfl_xor(part, 32);
    const float inv_scale = 1.0f / (8.0f + 1e-6f);
    const float logit = part * inv_scale;
    float mx = logit;
#pragma unroll
    for (int off = 1; off < 32; off <<= 1) mx = fmaxf(mx, __shfl_xor(mx, off));
    const float e = expf(logit - mx);
    float s = e;
#pragma unroll
    for (int off = 1; off < 32; off <<= 1) s += __shfl_xor(s, off);
    if (half == 0) a_s[wid][kk] = e / s;
    __syncthreads();

    float4 acc = make_float4(0.f, 0.f, 0.f, 0.f);
#pragma unroll
    for (int k2 = 0; k2 < 32; k2++) {
        const float w = a_s[wid][k2];
        const float4 rv = *(const float4*)&rv_s[k2][lane << 2];
        acc.x += w * rv.x; acc.y += w * rv.y; acc.z += w * rv.z; acc.w += w * rv.w;
    }
    const float asig = 1.f / (1.f + expf(-alpha[0]));
    float* spr = sp + (size_t)g * 256 + (lane << 2);
    float4 spv = *(float4*)spr;
    float4 o;
    o.x = asig * acc.x + (1.f - asig) * spv.x;
    o.y = asig * acc.y + (1.f - asig) * spv.y;
    o.z = asig * acc.z + (1.f - asig) * spv.z;
    o.w = asig * acc.w + (1.f - asig) * spv.w;
    *(float4*)spr = o;
}

// ============================================================================
// Kernel G: fused = fuse_w @ combined + fuse_b ; out = x + fused ; channel LN.
// Block: all 256 outputs x 32 positions.  K=256 in chunks of 32.
// ============================================================================
__global__ __launch_bounds__(256) void fuse_ln_kernel(
    const float* __restrict__ comb, const float* __restrict__ fuse_w,
    const float* __restrict__ fuse_b, const float* __restrict__ x,
    const float* __restrict__ ln_g, const float* __restrict__ ln_b,
    float* __restrict__ out)
{
    const int t = threadIdx.x;
    const int n0 = blockIdx.x << 5;
    const int b = blockIdx.y;

    __shared__ float smem[32 * 256 + 32 * 36];
    float (*Ws)[256] = (float (*)[256])smem;             // during GEMM
    float (*cs)[36] = (float (*)[36])(smem + 32 * 256);  // during GEMM
    float (*Fs)[260] = (float (*)[260])smem;             // epilogue overlay
    __shared__ float red1[8][32], red2[8][32];
    __shared__ float mu_s[32], rs_s[32];

    const int og = t & 63;   // o = og*4 + i
    const int ng = t >> 6;   // n = ng*8 + j
    float acc[4][8];
#pragma unroll
    for (int i = 0; i < 4; i++)
#pragma unroll
        for (int j = 0; j < 8; j++) acc[i][j] = 0.f;

    const int cl = (t << 2) & 31;
    const int nl = t >> 3;

    for (int c0 = 0; c0 < 256; c0 += 32) {
        __syncthreads();
        {   // stage Ws[c][o] = fuse_w[o][c0+c]
            const float* wr = fuse_w + (size_t)t * 256 + c0;
#pragma unroll
            for (int j = 0; j < 8; j++) {
                float4 w4 = *(const float4*)(wr + (j << 2));
                Ws[(j << 2) + 0][t] = w4.x;
                Ws[(j << 2) + 1][t] = w4.y;
                Ws[(j << 2) + 2][t] = w4.z;
                Ws[(j << 2) + 3][t] = w4.w;
            }
        }
        {   // stage cs[c][n] = comb[n][c0+c]
            float4 c4 = *(const float4*)(
                comb + ((size_t)(b * 4096 + n0 + nl)) * 256 + c0 + cl);
            cs[cl + 0][nl] = c4.x;
            cs[cl + 1][nl] = c4.y;
            cs[cl + 2][nl] = c4.z;
            cs[cl + 3][nl] = c4.w;
        }
        __syncthreads();
#pragma unroll
        for (int cc = 0; cc < 32; cc++) {
            float4 w4 = *(float4*)&Ws[cc][og << 2];
            float4 ca = *(float4*)&cs[cc][ng << 3];
            float4 cb = *(float4*)&cs[cc][(ng << 3) + 4];
            float wv[4] = {w4.x, w4.y, w4.z, w4.w};
            float cv[8] = {ca.x, ca.y, ca.z, ca.w, cb.x, cb.y, cb.z, cb.w};
#pragma unroll
            for (int i = 0; i < 4; i++)
#pragma unroll
                for (int j = 0; j < 8; j++) acc[i][j] += wv[i] * cv[j];
        }
    }

    __syncthreads();
#pragma unroll
    for (int i = 0; i < 4; i++) {
        const int o = (og << 2) + i;
        const float fb = fuse_b[o];
        const float* xr = x + ((size_t)(b * 256 + o)) * 4096 + n0 + (ng << 3);
        float4 xa = *(const float4*)xr;
        float4 xb = *(const float4*)(xr + 4);
        float xv[8] = {xa.x, xa.y, xa.z, xa.w, xb.x, xb.y, xb.z, xb.w};
#pragma unroll
        for (int j = 0; j < 8; j++)
            Fs[(ng << 3) + j][o] = acc[i][j] + fb + xv[j];
    }
    __syncthreads();
    {
        const int n = t & 31, part = t >> 5;
        float s1 = 0.f, s2 = 0.f;
#pragma unroll
        for (int i = 0; i < 32; i++) {
            const float v = Fs[n][(part << 5) + i];
            s1 += v; s2 += v * v;
        }
        red1[part][n] = s1; red2[part][n] = s2;
    }
    __syncthreads();
    if (t < 32) {
        float s1 = 0.f, s2 = 0.f;
#pragma unroll
        for (int p = 0; p < 8; p++) { s1 += red1[p][t]; s2 += red2[p][t]; }
        const float mean = s1 * (1.f / 256.f);
        const float var = s2 * (1.f / 256.f) - mean * mean;
        mu_s[t] = mean;
        rs_s[t] = rsqrtf(var + 1e-5f);
    }
    __syncthreads();
#pragma unroll
    for (int j = 0; j < 32; j++) {
        const int idx = (j << 8) + t;
        const int o = idx >> 5, n = idx & 31;
        const float v = (Fs[n][o] - mu_s[n]) * rs_s[n] * ln_g[o] + ln_b[o];
        out[((size_t)(b * 256 + o)) * 4096 + n0 + n] = v;
    }
}

// ============================================================================
extern "C" void kernel_launch(void* const* d_in, const int* in_sizes, int n_in,
                              void* d_out, int out_size, void* d_ws, size_t ws_size,
                              hipStream_t stream)
{
    const float* x = (const float*)d_in[0];
    const float* sem_w = (const float*)d_in[1];
    const float* sem_b = (const float*)d_in[2];
    const float* q_w = (const float*)d_in[3];
    const float* k_w = (const float*)d_in[4];
    const float* v_w = (const float*)d_in[5];
    const float* fuse_w = (const float*)d_in[6];
    const float* fuse_b = (const float*)d_in[7];
    const float* alpha = (const float*)d_in[8];
    const float* ln_g = (const float*)d_in[9];
    const float* ln_b = (const float*)d_in[10];
    float* out = (float*)d_out;

    char* ws = (char*)d_ws;
    float* Y   = (float*)(ws);              // 2*4096*416 f = 13,631,488 B
    float* SP  = (float*)(ws + 13631488);   // 2*4096*256 f =  8,388,608 B
    float* P   = (float*)(ws + 22020096);   // 64*10240 f   =  2,621,440 B
    float* REG = (float*)(ws + 24641536);   // 2*10240 f    =     81,920 B
    int*   HR  = (int*)  (ws + 24723456);   // 8192 i       =     32,768 B
    int*   TI  = (int*)  (ws + 24756224);   // 16384 i      =     65,536 B
    // total 24,821,760 B

    proj_kernel<<<dim3(64, 7, 2), 256, 0, stream>>>(x, sem_w, sem_b, q_w, k_w, v_w, Y);
    semsoft_kernel<<<32, 256, 0, stream>>>(Y, HR);
    region_partial_kernel<<<dim3(32, 2), 256, 0, stream>>>(Y, P);
    region_reduce_kernel<<<80, 256, 0, stream>>>(P, REG);
    topk_sem_kernel<<<dim3(32, 2), 256, 0, stream>>>(Y, TI);
    sparse_attn_kernel<<<2048, 256, 0, stream>>>(Y, HR, TI, SP);
    combine_kernel<<<2048, 256, 0, stream>>>(Y, REG, alpha, SP);
    fuse_ln_kernel<<<dim3(128, 2), 256, 0, stream>>>(SP, fuse_w, fuse_b, x, ln_g, ln_b, out);
}

// Round 3
// 331.572 us; speedup vs baseline: 1.1150x; 1.1150x over previous
//
#include <hip/hip_runtime.h>
#include <math.h>

// Problem shape (fixed): B=2, C=256, H=W=64 -> N=4096, d=64, K=32, M=256, topk=8
#define QOFF 32
#define KOFF 96
#define VOFF 160
#define NSUB 8

// ============================================================================
// Kernel A: fused projection GEMM.  Y[b][n][0..415] = {sem_logits(32), q(64),
// k(64), v(256)} ; Y row-major position rows of 416 floats.
// ============================================================================
__global__ __launch_bounds__(256) void proj_kernel(
    const float* __restrict__ x,
    const float* __restrict__ sem_w, const float* __restrict__ sem_b,
    const float* __restrict__ q_w, const float* __restrict__ k_w,
    const float* __restrict__ v_w, float* __restrict__ Y)
{
    const int t = threadIdx.x;
    const int n0 = blockIdx.x * 64;
    const int oc0 = blockIdx.y * 64;
    const int b = blockIdx.z;
    const int ty = t >> 4, tx = t & 15;

    __shared__ float As[16][68];
    __shared__ float Bs[16][64];

    float acc[4][4];
#pragma unroll
    for (int i = 0; i < 4; i++)
#pragma unroll
        for (int j = 0; j < 4; j++) acc[i][j] = 0.f;

    const int oc_l = t >> 2;
    const int cp = t & 3;
    const int oc_g = oc0 + oc_l;
    const float* wrow = nullptr;
    if (oc_g < 32) wrow = sem_w + oc_g * 256;
    else if (oc_g < 96) wrow = q_w + (oc_g - 32) * 256;
    else if (oc_g < 160) wrow = k_w + (oc_g - 96) * 256;
    else if (oc_g < 416) wrow = v_w + (oc_g - 160) * 256;

    const int bk = t >> 4;
    const int bn = (t & 15) << 2;

    for (int c0 = 0; c0 < 256; c0 += 16) {
        __syncthreads();
        float4 w4 = make_float4(0.f, 0.f, 0.f, 0.f);
        if (wrow) w4 = *(const float4*)(wrow + c0 + (cp << 2));
        As[(cp << 2) + 0][oc_l] = w4.x;
        As[(cp << 2) + 1][oc_l] = w4.y;
        As[(cp << 2) + 2][oc_l] = w4.z;
        As[(cp << 2) + 3][oc_l] = w4.w;
        *(float4*)&Bs[bk][bn] =
            *(const float4*)(x + ((size_t)(b * 256 + c0 + bk)) * 4096 + n0 + bn);
        __syncthreads();
#pragma unroll
        for (int kk = 0; kk < 16; kk++) {
            float4 a4 = *(float4*)&As[kk][ty << 2];
            float4 b4 = *(float4*)&Bs[kk][tx << 2];
            acc[0][0] += a4.x * b4.x; acc[0][1] += a4.x * b4.y;
            acc[0][2] += a4.x * b4.z; acc[0][3] += a4.x * b4.w;
            acc[1][0] += a4.y * b4.x; acc[1][1] += a4.y * b4.y;
            acc[1][2] += a4.y * b4.z; acc[1][3] += a4.y * b4.w;
            acc[2][0] += a4.z * b4.x; acc[2][1] += a4.z * b4.y;
            acc[2][2] += a4.z * b4.z; acc[2][3] += a4.z * b4.w;
            acc[3][0] += a4.w * b4.x; acc[3][1] += a4.w * b4.y;
            acc[3][2] += a4.w * b4.z; acc[3][3] += a4.w * b4.w;
        }
    }

    if (oc0 + (ty << 2) < 416) {
        float bias[4];
#pragma unroll
        for (int i = 0; i < 4; i++) {
            int oc = oc0 + (ty << 2) + i;
            bias[i] = (oc < 32) ? sem_b[oc] : 0.f;
        }
#pragma unroll
        for (int j = 0; j < 4; j++) {
            int n = n0 + (tx << 2) + j;
            float4 o4 = make_float4(acc[0][j] + bias[0], acc[1][j] + bias[1],
                                    acc[2][j] + bias[2], acc[3][j] + bias[3]);
            *(float4*)(Y + ((size_t)(b * 4096 + n)) * 416 + oc0 + (ty << 2)) = o4;
        }
    }
}

// ============================================================================
// Kernel B: per-position softmax over the 32 sem logits (in place) + argmax.
// ============================================================================
__global__ __launch_bounds__(256) void semsoft_kernel(float* __restrict__ Y,
                                                      int* __restrict__ hr)
{
    const int g = blockIdx.x * 256 + threadIdx.x;
    float* row = Y + (size_t)g * 416;
    float v[32];
#pragma unroll
    for (int i = 0; i < 8; i++) *(float4*)&v[i * 4] = *(float4*)&row[i * 4];
    float mx = v[0]; int am = 0;
#pragma unroll
    for (int kk = 1; kk < 32; kk++) if (v[kk] > mx) { mx = v[kk]; am = kk; }
    float s = 0.f;
#pragma unroll
    for (int kk = 0; kk < 32; kk++) { v[kk] = expf(v[kk] - mx); s += v[kk]; }
    const float inv = 1.f / s;
#pragma unroll
    for (int kk = 0; kk < 32; kk++) v[kk] *= inv;
#pragma unroll
    for (int i = 0; i < 8; i++) *(float4*)&row[i * 4] = *(float4*)&v[i * 4];
    hr[g] = am;
}

// ============================================================================
// Kernel B2: bin positions by hard region.  cnt must be pre-zeroed.
// ============================================================================
__global__ __launch_bounds__(256) void bin_kernel(
    const int* __restrict__ hr, int* __restrict__ cnt, int* __restrict__ plist)
{
    const int g = blockIdx.x * 256 + threadIdx.x;   // b*4096+n
    const int b = g >> 12, n = g & 4095;
    const int r = hr[g];
    const int slot = atomicAdd(&cnt[b * 32 + r], 1);
    plist[((size_t)(b * 32 + r)) * 4096 + slot] = n;
}

// ============================================================================
// Kernel C: region_k / region_v chunk partials (8-row batched staging).
// ============================================================================
__global__ __launch_bounds__(256) void region_partial_kernel(
    const float* __restrict__ Y, float* __restrict__ P)
{
    const int ch = blockIdx.x, b = blockIdx.y;
    const int t = threadIdx.x;
    __shared__ float row_s[8][420];
    const int kset = t & 7;
    const int dds = t >> 3;
    float acc[4][10];
#pragma unroll
    for (int i = 0; i < 4; i++)
#pragma unroll
        for (int j = 0; j < 10; j++) acc[i][j] = 0.f;
    const size_t gbase = (size_t)(b * 4096 + ch * 128);
    for (int r0 = 0; r0 < 128; r0 += 8) {
        __syncthreads();
#pragma unroll
        for (int r = 0; r < 8; r++) {
            const float* rp = Y + (gbase + r0 + r) * 416;
            row_s[r][t] = rp[t];
            if (t < 160) row_s[r][t + 256] = rp[t + 256];
        }
        __syncthreads();
#pragma unroll
        for (int r = 0; r < 8; r++) {
            float sv[4], kv[10];
#pragma unroll
            for (int i = 0; i < 4; i++) sv[i] = row_s[r][(kset << 2) + i];
#pragma unroll
            for (int j = 0; j < 10; j++) kv[j] = row_s[r][96 + dds * 10 + j];
#pragma unroll
            for (int i = 0; i < 4; i++)
#pragma unroll
                for (int j = 0; j < 10; j++) acc[i][j] += sv[i] * kv[j];
        }
    }
    float* Pb = P + ((size_t)(b * 32 + ch)) * 10240;
#pragma unroll
    for (int i = 0; i < 4; i++)
#pragma unroll
        for (int j = 0; j < 10; j++)
            Pb[((kset << 2) + i) * 320 + dds * 10 + j] = acc[i][j];
}

__global__ __launch_bounds__(256) void region_reduce_kernel(
    const float* __restrict__ P, float* __restrict__ region)
{
    const int idx = blockIdx.x * 256 + threadIdx.x;
    if (idx >= 2 * 10240) return;
    const int b = idx / 10240, rem = idx - b * 10240;
    float s = 0.f;
    for (int ch = 0; ch < 32; ch++)
        s += P[((size_t)(b * 32 + ch)) * 10240 + rem];
    region[(size_t)b * 10240 + rem] = s;
}

// ============================================================================
// Kernel D: top-256 indices of sem[b][k][:] over N=4096 (set semantics).
// ============================================================================
__global__ __launch_bounds__(256) void topk_sem_kernel(
    const float* __restrict__ Y, int* __restrict__ ti)
{
    const int kreg = blockIdx.x, b = blockIdx.y;
    const int t = threadIdx.x;
    __shared__ int wpart[4];
    __shared__ int sh_eq[256];
    __shared__ int ctr;

    unsigned int uv[16];
    const int nbase = t * 16;
#pragma unroll
    for (int i = 0; i < 16; i++) {
        float v = Y[((size_t)(b * 4096 + nbase + i)) * 416 + kreg];
        unsigned int u = __float_as_uint(v);
        uv[i] = (u & 0x80000000u) ? ~u : (u | 0x80000000u);
    }
    unsigned long long lo = 0ull, hi = 0xFFFFFFFFull;
    while (lo < hi) {
        const unsigned int mid = (unsigned int)((lo + hi + 1ull) >> 1);
        int c = 0;
#pragma unroll
        for (int i = 0; i < 16; i++) c += (uv[i] >= mid) ? 1 : 0;
#pragma unroll
        for (int off = 1; off < 64; off <<= 1) c += __shfl_xor(c, off);
        __syncthreads();
        if ((t & 63) == 0) wpart[t >> 6] = c;
        __syncthreads();
        const int tot = wpart[0] + wpart[1] + wpart[2] + wpart[3];
        if (tot >= 256) lo = mid; else hi = (unsigned long long)mid - 1ull;
    }
    const unsigned int T = (unsigned int)lo;
    int cgt = 0, ceq = 0;
#pragma unroll
    for (int i = 0; i < 16; i++) { cgt += (uv[i] > T) ? 1 : 0; ceq += (uv[i] == T) ? 1 : 0; }
    int cg = cgt;
#pragma unroll
    for (int off = 1; off < 64; off <<= 1) cg += __shfl_xor(cg, off);
    __syncthreads();
    if ((t & 63) == 0) wpart[t >> 6] = cg;
    sh_eq[t] = ceq;
    if (t == 0) ctr = 0;
    __syncthreads();
    const int c1 = wpart[0] + wpart[1] + wpart[2] + wpart[3];
    int eqbase = 0;
    for (int i = 0; i < t; i++) eqbase += sh_eq[i];
    int* outp = ti + ((size_t)(b * 32 + kreg)) * 256;
    int seen = 0;
#pragma unroll
    for (int i = 0; i < 16; i++) {
        if (uv[i] > T) {
            int pos = atomicAdd(&ctr, 1);
            outp[pos] = nbase + i;
        } else if (uv[i] == T) {
            int r = eqbase + seen; seen++;
            if (c1 + r < 256) outp[c1 + r] = nbase + i;
        }
    }
}

// ============================================================================
// Kernel E: region-grouped sparse attention.
// Block = (b,region, sub-chunk). Pool K staged ONCE per block into LDS
// (transposed, 2 halves of 128 keys). Each wave: 4 positions per pass,
// 2 keys/lane, top-8 fully in registers.
// ============================================================================
__global__ __launch_bounds__(256) void sparse_attn_kernel(
    const float* __restrict__ Y, const int* __restrict__ cnt,
    const int* __restrict__ plist, const int* __restrict__ ti,
    float* __restrict__ sp)
{
    const int rb = blockIdx.x;          // b*32+region
    const int sub = blockIdx.y;         // 0..NSUB-1
    const int b = rb >> 5;
    const int t = threadIdx.x, wid = t >> 6, lane = t & 63;

    const int count = cnt[rb];
    const int chunk = (count + NSUB - 1) / NSUB;
    const int p0 = sub * chunk;
    const int p1 = min(p0 + chunk, count);
    if (p1 <= p0) return;
    const int npass = (p1 - p0 + 15) >> 4;

    __shared__ int pool_s[256];          // 1 KB
    __shared__ float K_sT[64][128];      // 32 KB  [j][key in half]
    __shared__ float q_sT[4][64][4];     // 4 KB   [wid][j][pos]
    __shared__ float sims_s[4][4][256];  // 16 KB  [wid][pos][key]

    if (t < 64)
        *(int4*)&pool_s[t << 2] = *(const int4*)(ti + (size_t)rb * 256 + (t << 2));
    __syncthreads();

    const float inv_scale = 1.0f / (8.0f + 1e-6f);
    const int* myplist = plist + (size_t)rb * 4096;
    const int krow = t >> 1;            // 0..127: key within half
    const int jh = t & 1;               // j half (0..31 / 32..63)

    for (int pass = 0; pass < npass; pass++) {
        int gg[4]; bool val[4];
#pragma unroll
        for (int p = 0; p < 4; p++) {
            const int idx = p0 + (pass << 4) + (wid << 2) + p;
            val[p] = (idx < p1);
            const int n = myplist[val[p] ? idx : p0];
            gg[p] = (b << 12) + n;
            q_sT[wid][lane][p] = Y[(size_t)gg[p] * 416 + QOFF + lane];
        }

        for (int half = 0; half < 2; half++) {
            __syncthreads();   // prev compute done; q_sT visible
            {   // stage K half: 2 threads per key-row, 32 floats each
                const int kidx = pool_s[(half << 7) + krow];
                const float* kr = Y + ((size_t)((b << 12) + kidx)) * 416 + KOFF + (jh << 5);
#pragma unroll
                for (int jj = 0; jj < 8; jj++) {
                    float4 kv = *(const float4*)(kr + (jj << 2));
                    const int jb = (jh << 5) + (jj << 2);
                    K_sT[jb + 0][krow] = kv.x;
                    K_sT[jb + 1][krow] = kv.y;
                    K_sT[jb + 2][krow] = kv.z;
                    K_sT[jb + 3][krow] = kv.w;
                }
            }
            __syncthreads();
            float a00 = 0.f, a01 = 0.f, a10 = 0.f, a11 = 0.f;
            float a20 = 0.f, a21 = 0.f, a30 = 0.f, a31 = 0.f;
#pragma unroll
            for (int j = 0; j < 64; j++) {
                const float2 kv = *(const float2*)&K_sT[j][lane << 1];
                const float4 q4 = *(const float4*)&q_sT[wid][j][0];
                a00 += q4.x * kv.x; a01 += q4.x * kv.y;
                a10 += q4.y * kv.x; a11 += q4.y * kv.y;
                a20 += q4.z * kv.x; a21 += q4.z * kv.y;
                a30 += q4.w * kv.x; a31 += q4.w * kv.y;
            }
            const int sbase = (half << 7) + (lane << 1);
            *(float2*)&sims_s[wid][0][sbase] = make_float2(a00 * inv_scale, a01 * inv_scale);
            *(float2*)&sims_s[wid][1][sbase] = make_float2(a10 * inv_scale, a11 * inv_scale);
            *(float2*)&sims_s[wid][2][sbase] = make_float2(a20 * inv_scale, a21 * inv_scale);
            *(float2*)&sims_s[wid][3][sbase] = make_float2(a30 * inv_scale, a31 * inv_scale);
        }
        // cross-lane sims visibility within the wave
        asm volatile("s_waitcnt lgkmcnt(0)" ::: "memory");

#pragma unroll
        for (int p = 0; p < 4; p++) {
            if (!val[p]) continue;
            float4 sv = *(const float4*)&sims_s[wid][p][lane << 2];
            float s0 = sv.x, s1 = sv.y, s2 = sv.z, s3 = sv.w;
            float topv[8]; int topm[8];
#pragma unroll
            for (int sel = 0; sel < 8; sel++) {
                float bv = s0; int bm = (lane << 2);
                if (s1 > bv) { bv = s1; bm = (lane << 2) + 1; }
                if (s2 > bv) { bv = s2; bm = (lane << 2) + 2; }
                if (s3 > bv) { bv = s3; bm = (lane << 2) + 3; }
#pragma unroll
                for (int off = 1; off < 64; off <<= 1) {
                    const float ov = __shfl_xor(bv, off);
                    const int om = __shfl_xor(bm, off);
                    if (ov > bv || (ov == bv && om < bm)) { bv = ov; bm = om; }
                }
                topv[sel] = bv; topm[sel] = bm;
                const bool own = (lane == (bm >> 2));
                const int sl = bm & 3;
                s0 = (own && sl == 0) ? -3e38f : s0;
                s1 = (own && sl == 1) ? -3e38f : s1;
                s2 = (own && sl == 2) ? -3e38f : s2;
                s3 = (own && sl == 3) ? -3e38f : s3;
            }
            const float mx = topv[0];
            float att[8]; float esum = 0.f;
#pragma unroll
            for (int j = 0; j < 8; j++) { att[j] = expf(topv[j] - mx); esum += att[j]; }
            const float inv = 1.f / esum;
            float4 acc = make_float4(0.f, 0.f, 0.f, 0.f);
#pragma unroll
            for (int j = 0; j < 8; j++) {
                const int actual = pool_s[topm[j]];
                const float4 vv = *(const float4*)(
                    Y + ((size_t)((b << 12) + actual)) * 416 + VOFF + (lane << 2));
                const float w = att[j] * inv;
                acc.x += w * vv.x; acc.y += w * vv.y;
                acc.z += w * vv.z; acc.w += w * vv.w;
            }
            *(float4*)(sp + (size_t)gg[p] * 256 + (lane << 2)) = acc;
        }
    }
}

// ============================================================================
// Kernel F: dense region-attention branch + combine (in place over sp).
// 256 blocks x 32 positions; region data + q staged once per block.
// ============================================================================
__global__ __launch_bounds__(256) void combine_kernel(
    const float* __restrict__ Y, const float* __restrict__ region,
    const float* __restrict__ alpha, float* __restrict__ sp)
{
    const int t = threadIdx.x, wid = t >> 6, lane = t & 63;
    const int b = blockIdx.y;
    const int n0 = blockIdx.x << 5;     // 32 positions per block
    __shared__ float rk_s[32][65];      // 8.3 KB
    __shared__ float rv_s[32][256];     // 32 KB
    __shared__ float q_all[32][64];     // 8 KB

    const float* reg = region + (size_t)b * 10240;
    for (int idx = t; idx < 10240; idx += 256) {
        const int kk = idx / 320, dd = idx - kk * 320;
        const float v = reg[idx];
        if (dd < 64) rk_s[kk][dd] = v; else rv_s[kk][dd - 64] = v;
    }
    const size_t g0 = (size_t)(b << 12) + n0;
    for (int idx = t; idx < 2048; idx += 256)
        q_all[idx >> 6][idx & 63] = Y[(g0 + (idx >> 6)) * 416 + QOFF + (idx & 63)];
    __syncthreads();

    const float asig = 1.f / (1.f + expf(-alpha[0]));
    const float inv_scale = 1.0f / (8.0f + 1e-6f);
    const int kk = lane & 31, half = lane >> 5;

    for (int pp = 0; pp < 8; pp++) {
        const int n_l = (wid << 3) + pp;
        const size_t g = g0 + n_l;
        float part = 0.f;
        {
            const float* qr = &q_all[n_l][half << 5];
            const float* rkr = &rk_s[kk][half << 5];
#pragma unroll
            for (int j = 0; j < 32; j++) part += qr[j] * rkr[j];
        }
        part += __shfl_xor(part, 32);
        const float logit = part * inv_scale;
        float mx = logit;
#pragma unroll
        for (int off = 1; off < 32; off <<= 1) mx = fmaxf(mx, __shfl_xor(mx, off));
        const float e = expf(logit - mx);
        float s = e;
#pragma unroll
        for (int off = 1; off < 32; off <<= 1) s += __shfl_xor(s, off);
        const float w_own = e / s;   // weight for region kk (both halves identical)

        float4 acc = make_float4(0.f, 0.f, 0.f, 0.f);
#pragma unroll
        for (int k2 = 0; k2 < 32; k2++) {
            const float w = __shfl(w_own, k2);
            const float4 rv = *(const float4*)&rv_s[k2][lane << 2];
            acc.x += w * rv.x; acc.y += w * rv.y;
            acc.z += w * rv.z; acc.w += w * rv.w;
        }
        float* spr = sp + g * 256 + (lane << 2);
        float4 spv = *(float4*)spr;
        float4 o;
        o.x = asig * acc.x + (1.f - asig) * spv.x;
        o.y = asig * acc.y + (1.f - asig) * spv.y;
        o.z = asig * acc.z + (1.f - asig) * spv.z;
        o.w = asig * acc.w + (1.f - asig) * spv.w;
        *(float4*)spr = o;
    }
}

// ============================================================================
// Kernel G: fused = fuse_w @ combined + fuse_b ; out = x + fused ; channel LN.
// ============================================================================
__global__ __launch_bounds__(256) void fuse_ln_kernel(
    const float* __restrict__ comb, const float* __restrict__ fuse_w,
    const float* __restrict__ fuse_b, const float* __restrict__ x,
    const float* __restrict__ ln_g, const float* __restrict__ ln_b,
    float* __restrict__ out)
{
    const int t = threadIdx.x;
    const int n0 = blockIdx.x << 5;
    const int b = blockIdx.y;

    __shared__ float smem[32 * 256 + 32 * 36];
    float (*Ws)[256] = (float (*)[256])smem;
    float (*cs)[36] = (float (*)[36])(smem + 32 * 256);
    float (*Fs)[260] = (float (*)[260])smem;
    __shared__ float red1[8][32], red2[8][32];
    __shared__ float mu_s[32], rs_s[32];

    const int og = t & 63;
    const int ng = t >> 6;
    float acc[4][8];
#pragma unroll
    for (int i = 0; i < 4; i++)
#pragma unroll
        for (int j = 0; j < 8; j++) acc[i][j] = 0.f;

    const int cl = (t << 2) & 31;
    const int nl = t >> 3;

    for (int c0 = 0; c0 < 256; c0 += 32) {
        __syncthreads();
        {
            const float* wr = fuse_w + (size_t)t * 256 + c0;
#pragma unroll
            for (int j = 0; j < 8; j++) {
                float4 w4 = *(const float4*)(wr + (j << 2));
                Ws[(j << 2) + 0][t] = w4.x;
                Ws[(j << 2) + 1][t] = w4.y;
                Ws[(j << 2) + 2][t] = w4.z;
                Ws[(j << 2) + 3][t] = w4.w;
            }
        }
        {
            float4 c4 = *(const float4*)(
                comb + ((size_t)(b * 4096 + n0 + nl)) * 256 + c0 + cl);
            cs[cl + 0][nl] = c4.x;
            cs[cl + 1][nl] = c4.y;
            cs[cl + 2][nl] = c4.z;
            cs[cl + 3][nl] = c4.w;
        }
        __syncthreads();
#pragma unroll
        for (int cc = 0; cc < 32; cc++) {
            float4 w4 = *(float4*)&Ws[cc][og << 2];
            float4 ca = *(float4*)&cs[cc][ng << 3];
            float4 cb = *(float4*)&cs[cc][(ng << 3) + 4];
            float wv[4] = {w4.x, w4.y, w4.z, w4.w};
            float cv[8] = {ca.x, ca.y, ca.z, ca.w, cb.x, cb.y, cb.z, cb.w};
#pragma unroll
            for (int i = 0; i < 4; i++)
#pragma unroll
                for (int j = 0; j < 8; j++) acc[i][j] += wv[i] * cv[j];
        }
    }

    __syncthreads();
#pragma unroll
    for (int i = 0; i < 4; i++) {
        const int o = (og << 2) + i;
        const float fb = fuse_b[o];
        const float* xr = x + ((size_t)(b * 256 + o)) * 4096 + n0 + (ng << 3);
        float4 xa = *(const float4*)xr;
        float4 xb = *(const float4*)(xr + 4);
        float xv[8] = {xa.x, xa.y, xa.z, xa.w, xb.x, xb.y, xb.z, xb.w};
#pragma unroll
        for (int j = 0; j < 8; j++)
            Fs[(ng << 3) + j][o] = acc[i][j] + fb + xv[j];
    }
    __syncthreads();
    {
        const int n = t & 31, part = t >> 5;
        float s1 = 0.f, s2 = 0.f;
#pragma unroll
        for (int i = 0; i < 32; i++) {
            const float v = Fs[n][(part << 5) + i];
            s1 += v; s2 += v * v;
        }
        red1[part][n] = s1; red2[part][n] = s2;
    }
    __syncthreads();
    if (t < 32) {
        float s1 = 0.f, s2 = 0.f;
#pragma unroll
        for (int p = 0; p < 8; p++) { s1 += red1[p][t]; s2 += red2[p][t]; }
        const float mean = s1 * (1.f / 256.f);
        const float var = s2 * (1.f / 256.f) - mean * mean;
        mu_s[t] = mean;
        rs_s[t] = rsqrtf(var + 1e-5f);
    }
    __syncthreads();
#pragma unroll
    for (int j = 0; j < 32; j++) {
        const int idx = (j << 8) + t;
        const int o = idx >> 5, n = idx & 31;
        const float v = (Fs[n][o] - mu_s[n]) * rs_s[n] * ln_g[o] + ln_b[o];
        out[((size_t)(b * 256 + o)) * 4096 + n0 + n] = v;
    }
}

// ============================================================================
extern "C" void kernel_launch(void* const* d_in, const int* in_sizes, int n_in,
                              void* d_out, int out_size, void* d_ws, size_t ws_size,
                              hipStream_t stream)
{
    const float* x = (const float*)d_in[0];
    const float* sem_w = (const float*)d_in[1];
    const float* sem_b = (const float*)d_in[2];
    const float* q_w = (const float*)d_in[3];
    const float* k_w = (const float*)d_in[4];
    const float* v_w = (const float*)d_in[5];
    const float* fuse_w = (const float*)d_in[6];
    const float* fuse_b = (const float*)d_in[7];
    const float* alpha = (const float*)d_in[8];
    const float* ln_g = (const float*)d_in[9];
    const float* ln_b = (const float*)d_in[10];
    float* out = (float*)d_out;

    char* ws = (char*)d_ws;
    float* Y    = (float*)(ws);              // 13,631,488 B
    float* SP   = (float*)(ws + 13631488);   //  8,388,608 B
    float* P    = (float*)(ws + 22020096);   //  2,621,440 B
    float* REG  = (float*)(ws + 24641536);   //     81,920 B
    int*   HR   = (int*)  (ws + 24723456);   //     32,768 B
    int*   TI   = (int*)  (ws + 24756224);   //     65,536 B
    int*   CNT  = (int*)  (ws + 24821760);   //        256 B
    int*   PLIST= (int*)  (ws + 24822016);   //  1,048,576 B -> total 25,870,592

    proj_kernel<<<dim3(64, 7, 2), 256, 0, stream>>>(x, sem_w, sem_b, q_w, k_w, v_w, Y);
    semsoft_kernel<<<32, 256, 0, stream>>>(Y, HR);
    hipMemsetAsync(CNT, 0, 256, stream);
    bin_kernel<<<32, 256, 0, stream>>>(HR, CNT, PLIST);
    region_partial_kernel<<<dim3(32, 2), 256, 0, stream>>>(Y, P);
    region_reduce_kernel<<<80, 256, 0, stream>>>(P, REG);
    topk_sem_kernel<<<dim3(32, 2), 256, 0, stream>>>(Y, TI);
    sparse_attn_kernel<<<dim3(64, NSUB), 256, 0, stream>>>(Y, CNT, PLIST, TI, SP);
    combine_kernel<<<dim3(128, 2), 256, 0, stream>>>(Y, REG, alpha, SP);
    fuse_ln_kernel<<<dim3(128, 2), 256, 0, stream>>>(SP, fuse_w, fuse_b, x, ln_g, ln_b, out);
}

// Round 5
// 329.425 us; speedup vs baseline: 1.1223x; 1.0065x over previous
//
#include <hip/hip_runtime.h>
#include <math.h>

// Problem shape (fixed): B=2, C=256, H=W=64 -> N=4096, d=64, K=32, M=256, topk=8
#define QOFF 32
#define KOFF 96
#define VOFF 160
#define NSUB 8

// ============================================================================
// Kernel A: fused projection GEMM.  Y[b][n][0..415] = {sem_logits(32), q(64),
// k(64), v(256)} ; Y row-major position rows of 416 floats.
// ============================================================================
__global__ __launch_bounds__(256) void proj_kernel(
    const float* __restrict__ x,
    const float* __restrict__ sem_w, const float* __restrict__ sem_b,
    const float* __restrict__ q_w, const float* __restrict__ k_w,
    const float* __restrict__ v_w, float* __restrict__ Y)
{
    const int t = threadIdx.x;
    const int n0 = blockIdx.x * 64;
    const int oc0 = blockIdx.y * 64;
    const int b = blockIdx.z;
    const int ty = t >> 4, tx = t & 15;

    __shared__ float As[16][68];
    __shared__ float Bs[16][64];

    float acc[4][4];
#pragma unroll
    for (int i = 0; i < 4; i++)
#pragma unroll
        for (int j = 0; j < 4; j++) acc[i][j] = 0.f;

    const int oc_l = t >> 2;
    const int cp = t & 3;
    const int oc_g = oc0 + oc_l;
    const float* wrow = nullptr;
    if (oc_g < 32) wrow = sem_w + oc_g * 256;
    else if (oc_g < 96) wrow = q_w + (oc_g - 32) * 256;
    else if (oc_g < 160) wrow = k_w + (oc_g - 96) * 256;
    else if (oc_g < 416) wrow = v_w + (oc_g - 160) * 256;

    const int bk = t >> 4;
    const int bn = (t & 15) << 2;

    for (int c0 = 0; c0 < 256; c0 += 16) {
        __syncthreads();
        float4 w4 = make_float4(0.f, 0.f, 0.f, 0.f);
        if (wrow) w4 = *(const float4*)(wrow + c0 + (cp << 2));
        As[(cp << 2) + 0][oc_l] = w4.x;
        As[(cp << 2) + 1][oc_l] = w4.y;
        As[(cp << 2) + 2][oc_l] = w4.z;
        As[(cp << 2) + 3][oc_l] = w4.w;
        *(float4*)&Bs[bk][bn] =
            *(const float4*)(x + ((size_t)(b * 256 + c0 + bk)) * 4096 + n0 + bn);
        __syncthreads();
#pragma unroll
        for (int kk = 0; kk < 16; kk++) {
            float4 a4 = *(float4*)&As[kk][ty << 2];
            float4 b4 = *(float4*)&Bs[kk][tx << 2];
            acc[0][0] += a4.x * b4.x; acc[0][1] += a4.x * b4.y;
            acc[0][2] += a4.x * b4.z; acc[0][3] += a4.x * b4.w;
            acc[1][0] += a4.y * b4.x; acc[1][1] += a4.y * b4.y;
            acc[1][2] += a4.y * b4.z; acc[1][3] += a4.y * b4.w;
            acc[2][0] += a4.z * b4.x; acc[2][1] += a4.z * b4.y;
            acc[2][2] += a4.z * b4.z; acc[2][3] += a4.z * b4.w;
            acc[3][0] += a4.w * b4.x; acc[3][1] += a4.w * b4.y;
            acc[3][2] += a4.w * b4.z; acc[3][3] += a4.w * b4.w;
        }
    }

    if (oc0 + (ty << 2) < 416) {
        float bias[4];
#pragma unroll
        for (int i = 0; i < 4; i++) {
            int oc = oc0 + (ty << 2) + i;
            bias[i] = (oc < 32) ? sem_b[oc] : 0.f;
        }
#pragma unroll
        for (int j = 0; j < 4; j++) {
            int n = n0 + (tx << 2) + j;
            float4 o4 = make_float4(acc[0][j] + bias[0], acc[1][j] + bias[1],
                                    acc[2][j] + bias[2], acc[3][j] + bias[3]);
            *(float4*)(Y + ((size_t)(b * 4096 + n)) * 416 + oc0 + (ty << 2)) = o4;
        }
    }
}

// ============================================================================
// Kernel B: per-position softmax over the 32 sem logits (in place) + argmax.
// ============================================================================
__global__ __launch_bounds__(256) void semsoft_kernel(float* __restrict__ Y,
                                                      int* __restrict__ hr)
{
    const int g = blockIdx.x * 256 + threadIdx.x;
    float* row = Y + (size_t)g * 416;
    float v[32];
#pragma unroll
    for (int i = 0; i < 8; i++) *(float4*)&v[i * 4] = *(float4*)&row[i * 4];
    float mx = v[0]; int am = 0;
#pragma unroll
    for (int kk = 1; kk < 32; kk++) if (v[kk] > mx) { mx = v[kk]; am = kk; }
    float s = 0.f;
#pragma unroll
    for (int kk = 0; kk < 32; kk++) { v[kk] = expf(v[kk] - mx); s += v[kk]; }
    const float inv = 1.f / s;
#pragma unroll
    for (int kk = 0; kk < 32; kk++) v[kk] *= inv;
#pragma unroll
    for (int i = 0; i < 8; i++) *(float4*)&row[i * 4] = *(float4*)&v[i * 4];
    hr[g] = am;
}

// ============================================================================
// Kernel B2: bin positions by hard region.  cnt must be pre-zeroed.
// ============================================================================
__global__ __launch_bounds__(256) void bin_kernel(
    const int* __restrict__ hr, int* __restrict__ cnt, int* __restrict__ plist)
{
    const int g = blockIdx.x * 256 + threadIdx.x;   // b*4096+n
    const int b = g >> 12, n = g & 4095;
    const int r = hr[g];
    const int slot = atomicAdd(&cnt[b * 32 + r], 1);
    plist[((size_t)(b * 32 + r)) * 4096 + slot] = n;
}

// ============================================================================
// Kernel C: region_k/v partials as a tiled GEMM.
// Block (ch, b, dg): out tile = 32k x 64dd over 128 positions.
// P[b][ch][k*320+dd] ; dd 0..63 -> k-rows, 64..319 -> v-rows (offset 96..415).
// ============================================================================
__global__ __launch_bounds__(256) void region_partial_kernel(
    const float* __restrict__ Y, float* __restrict__ P)
{
    const int ch = blockIdx.x;     // 0..31 (position chunk of 128)
    const int b  = blockIdx.y;     // 0..1
    const int dg = blockIdx.z;     // 0..4  (dd group of 64)
    const int t = threadIdx.x;
    __shared__ float sem_s[16][33];
    __shared__ float kv_s[16][68];
    const int kg = t >> 4;         // 0..15 -> k = kg*2 + {0,1}
    const int dq = t & 15;         // 0..15 -> dd = dq*4 .. +3
    float acc[2][4];
#pragma unroll
    for (int i = 0; i < 2; i++)
#pragma unroll
        for (int j = 0; j < 4; j++) acc[i][j] = 0.f;

    const size_t gbase = (size_t)(b * 4096 + ch * 128);
    const int sr = t >> 4, sc = (t & 15) << 2;   // kv staging coords
    for (int r0 = 0; r0 < 128; r0 += 16) {
        __syncthreads();
        {   // sem: 512 floats, 2 rounds of 256
            sem_s[t >> 5][t & 31] = Y[(gbase + r0 + (t >> 5)) * 416 + (t & 31)];
            const int i2 = t + 256;
            sem_s[i2 >> 5][i2 & 31] = Y[(gbase + r0 + (i2 >> 5)) * 416 + (i2 & 31)];
        }
        {   // kv: 16 rows x 64 floats
            *(float4*)&kv_s[sr][sc] =
                *(const float4*)(Y + (gbase + r0 + sr) * 416 + 96 + dg * 64 + sc);
        }
        __syncthreads();
#pragma unroll
        for (int r = 0; r < 16; r++) {
            const float s0 = sem_s[r][(kg << 1) + 0];
            const float s1 = sem_s[r][(kg << 1) + 1];
            const float4 kv = *(float4*)&kv_s[r][dq << 2];
            acc[0][0] += s0 * kv.x; acc[0][1] += s0 * kv.y;
            acc[0][2] += s0 * kv.z; acc[0][3] += s0 * kv.w;
            acc[1][0] += s1 * kv.x; acc[1][1] += s1 * kv.y;
            acc[1][2] += s1 * kv.z; acc[1][3] += s1 * kv.w;
        }
    }
    float* Pb = P + ((size_t)(b * 32 + ch)) * 10240 + dg * 64;
#pragma unroll
    for (int i = 0; i < 2; i++)
        *(float4*)&Pb[((kg << 1) + i) * 320 + (dq << 2)] =
            make_float4(acc[i][0], acc[i][1], acc[i][2], acc[i][3]);
}

__global__ __launch_bounds__(256) void region_reduce_kernel(
    const float* __restrict__ P, float* __restrict__ region)
{
    const int idx = blockIdx.x * 256 + threadIdx.x;
    if (idx >= 2 * 10240) return;
    const int b = idx / 10240, rem = idx - b * 10240;
    float s = 0.f;
    for (int ch = 0; ch < 32; ch++)
        s += P[((size_t)(b * 32 + ch)) * 10240 + rem];
    region[(size_t)b * 10240 + rem] = s;
}

// ============================================================================
// Kernel D: top-256 indices of sem[b][k][:] over N=4096 (set semantics).
// ============================================================================
__global__ __launch_bounds__(256) void topk_sem_kernel(
    const float* __restrict__ Y, int* __restrict__ ti)
{
    const int kreg = blockIdx.x, b = blockIdx.y;
    const int t = threadIdx.x;
    __shared__ int wpart[4];
    __shared__ int sh_eq[256];
    __shared__ int ctr;

    unsigned int uv[16];
    const int nbase = t * 16;
#pragma unroll
    for (int i = 0; i < 16; i++) {
        float v = Y[((size_t)(b * 4096 + nbase + i)) * 416 + kreg];
        unsigned int u = __float_as_uint(v);
        uv[i] = (u & 0x80000000u) ? ~u : (u | 0x80000000u);
    }
    unsigned long long lo = 0ull, hi = 0xFFFFFFFFull;
    while (lo < hi) {
        const unsigned int mid = (unsigned int)((lo + hi + 1ull) >> 1);
        int c = 0;
#pragma unroll
        for (int i = 0; i < 16; i++) c += (uv[i] >= mid) ? 1 : 0;
#pragma unroll
        for (int off = 1; off < 64; off <<= 1) c += __shfl_xor(c, off);
        __syncthreads();
        if ((t & 63) == 0) wpart[t >> 6] = c;
        __syncthreads();
        const int tot = wpart[0] + wpart[1] + wpart[2] + wpart[3];
        if (tot >= 256) lo = mid; else hi = (unsigned long long)mid - 1ull;
    }
    const unsigned int T = (unsigned int)lo;
    int cgt = 0, ceq = 0;
#pragma unroll
    for (int i = 0; i < 16; i++) { cgt += (uv[i] > T) ? 1 : 0; ceq += (uv[i] == T) ? 1 : 0; }
    int cg = cgt;
#pragma unroll
    for (int off = 1; off < 64; off <<= 1) cg += __shfl_xor(cg, off);
    __syncthreads();
    if ((t & 63) == 0) wpart[t >> 6] = cg;
    sh_eq[t] = ceq;
    if (t == 0) ctr = 0;
    __syncthreads();
    const int c1 = wpart[0] + wpart[1] + wpart[2] + wpart[3];
    int eqbase = 0;
    for (int i = 0; i < t; i++) eqbase += sh_eq[i];
    int* outp = ti + ((size_t)(b * 32 + kreg)) * 256;
    int seen = 0;
#pragma unroll
    for (int i = 0; i < 16; i++) {
        if (uv[i] > T) {
            int pos = atomicAdd(&ctr, 1);
            outp[pos] = nbase + i;
        } else if (uv[i] == T) {
            int r = eqbase + seen; seen++;
            if (c1 + r < 256) outp[c1 + r] = nbase + i;
        }
    }
}

// ============================================================================
// Kernel E: region-grouped sparse attention. Pool K staged ONCE per block
// (BOTH halves: all 256 keys, 64 KB). Each wave: 4 positions/pass,
// 4 key-slots/lane, top-8 fully in registers.
// ============================================================================
__global__ __launch_bounds__(256) void sparse_attn_kernel(
    const float* __restrict__ Y, const int* __restrict__ cnt,
    const int* __restrict__ plist, const int* __restrict__ ti,
    float* __restrict__ sp)
{
    const int rb = blockIdx.x;          // b*32+region
    const int sub = blockIdx.y;         // 0..NSUB-1
    const int b = rb >> 5;
    const int t = threadIdx.x, wid = t >> 6, lane = t & 63;

    int count = cnt[rb];
    count = min(max(count, 0), 4096);   // clamp: profiling-replay / poison safety
    const int chunk = (count + NSUB - 1) / NSUB;
    const int p0 = sub * chunk;
    const int p1 = min(p0 + chunk, count);
    if (p1 <= p0) return;
    const int npass = (p1 - p0 + 15) >> 4;

    __shared__ int pool_s[256];          // 1 KB
    __shared__ float K_sT[64][256];      // 64 KB  [j][key]
    __shared__ float q_sT[4][64][4];     // 4 KB   [wid][j][pos]

    if (t < 64)
        *(int4*)&pool_s[t << 2] = *(const int4*)(ti + (size_t)rb * 256 + (t << 2));
    __syncthreads();
    {   // stage ALL 256 keys: 2 threads per key, 32 floats each, 2 halves
        const int krow = t >> 1, jh = t & 1;
#pragma unroll
        for (int hh = 0; hh < 2; hh++) {
            const int key = (hh << 7) + krow;
            const int kidx = pool_s[key];
            const float* kr = Y + ((size_t)((b << 12) + kidx)) * 416 + KOFF + (jh << 5);
#pragma unroll
            for (int jj = 0; jj < 8; jj++) {
                float4 kv = *(const float4*)(kr + (jj << 2));
                const int jb = (jh << 5) + (jj << 2);
                K_sT[jb + 0][key] = kv.x;
                K_sT[jb + 1][key] = kv.y;
                K_sT[jb + 2][key] = kv.z;
                K_sT[jb + 3][key] = kv.w;
            }
        }
    }
    __syncthreads();

    const float inv_scale = 1.0f / (8.0f + 1e-6f);
    const int* myplist = plist + (size_t)rb * 4096;

    for (int pass = 0; pass < npass; pass++) {
        int gg[4]; bool val[4];
#pragma unroll
        for (int p = 0; p < 4; p++) {
            const int idx = p0 + (pass << 4) + (wid << 2) + p;
            val[p] = (idx < p1);
            const int n = myplist[val[p] ? idx : p0];
            gg[p] = (b << 12) + n;
            q_sT[wid][lane][p] = Y[(size_t)gg[p] * 416 + QOFF + lane];
        }
        // wave-level: all lanes' q writes drained before cross-lane reads
        asm volatile("s_waitcnt lgkmcnt(0)" ::: "memory");

        // sims: lane owns keys {2l, 2l+1, 128+2l, 128+2l+1} for 4 positions
        float a[4][4];
#pragma unroll
        for (int p = 0; p < 4; p++)
#pragma unroll
            for (int sl = 0; sl < 4; sl++) a[p][sl] = 0.f;
#pragma unroll
        for (int j = 0; j < 64; j++) {
            const float2 k0 = *(const float2*)&K_sT[j][lane << 1];
            const float2 k1 = *(const float2*)&K_sT[j][128 + (lane << 1)];
            const float4 q4 = *(const float4*)&q_sT[wid][j][0];
            a[0][0] += q4.x * k0.x; a[0][1] += q4.x * k0.y;
            a[0][2] += q4.x * k1.x; a[0][3] += q4.x * k1.y;
            a[1][0] += q4.y * k0.x; a[1][1] += q4.y * k0.y;
            a[1][2] += q4.y * k1.x; a[1][3] += q4.y * k1.y;
            a[2][0] += q4.z * k0.x; a[2][1] += q4.z * k0.y;
            a[2][2] += q4.z * k1.x; a[2][3] += q4.z * k1.y;
            a[3][0] += q4.w * k0.x; a[3][1] += q4.w * k0.y;
            a[3][2] += q4.w * k1.x; a[3][3] += q4.w * k1.y;
        }

#pragma unroll
        for (int p = 0; p < 4; p++) {
            if (!val[p]) continue;
            // key index per slot: 0->2l, 1->2l+1, 2->128+2l, 3->128+2l+1
            float s0 = a[p][0] * inv_scale, s1 = a[p][1] * inv_scale;
            float s2 = a[p][2] * inv_scale, s3 = a[p][3] * inv_scale;
            const int m0 = lane << 1;
            float topv[8]; int topm[8];
#pragma unroll
            for (int sel = 0; sel < 8; sel++) {
                float bv = s0; int bm = m0;
                if (s1 > bv) { bv = s1; bm = m0 + 1; }
                if (s2 > bv) { bv = s2; bm = 128 + m0; }
                if (s3 > bv) { bv = s3; bm = 128 + m0 + 1; }
#pragma unroll
                for (int off = 1; off < 64; off <<= 1) {
                    const float ov = __shfl_xor(bv, off);
                    const int om = __shfl_xor(bm, off);
                    if (ov > bv || (ov == bv && om < bm)) { bv = ov; bm = om; }
                }
                topv[sel] = bv; topm[sel] = bm;
                const int owner = (bm & 127) >> 1;
                const int sl = (bm & 1) | ((bm >> 7) << 1);
                if (lane == owner) {
                    s0 = (sl == 0) ? -3e38f : s0;
                    s1 = (sl == 1) ? -3e38f : s1;
                    s2 = (sl == 2) ? -3e38f : s2;
                    s3 = (sl == 3) ? -3e38f : s3;
                }
            }
            const float mx = topv[0];
            float att[8]; float esum = 0.f;
#pragma unroll
            for (int j = 0; j < 8; j++) { att[j] = expf(topv[j] - mx); esum += att[j]; }
            const float inv = 1.f / esum;
            float4 acc = make_float4(0.f, 0.f, 0.f, 0.f);
#pragma unroll
            for (int j = 0; j < 8; j++) {
                const int actual = pool_s[topm[j]];
                const float4 vv = *(const float4*)(
                    Y + ((size_t)((b << 12) + actual)) * 416 + VOFF + (lane << 2));
                const float w = att[j] * inv;
                acc.x += w * vv.x; acc.y += w * vv.y;
                acc.z += w * vv.z; acc.w += w * vv.w;
            }
            *(float4*)(sp + (size_t)gg[p] * 256 + (lane << 2)) = acc;
        }
    }
}

// ============================================================================
// Kernel F: dense region-attention branch + combine (in place over sp).
// 256 blocks x 32 positions; region data + q staged once per block.
// ============================================================================
__global__ __launch_bounds__(256) void combine_kernel(
    const float* __restrict__ Y, const float* __restrict__ region,
    const float* __restrict__ alpha, float* __restrict__ sp)
{
    const int t = threadIdx.x, wid = t >> 6, lane = t & 63;
    const int b = blockIdx.y;
    const int n0 = blockIdx.x << 5;     // 32 positions per block
    __shared__ float rk_s[32][65];      // 8.3 KB
    __shared__ float rv_s[32][256];     // 32 KB
    __shared__ float q_all[32][64];     // 8 KB

    const float* reg = region + (size_t)b * 10240;
    for (int idx = t; idx < 10240; idx += 256) {
        const int kk = idx / 320, dd = idx - kk * 320;
        const float v = reg[idx];
        if (dd < 64) rk_s[kk][dd] = v; else rv_s[kk][dd - 64] = v;
    }
    const size_t g0 = (size_t)(b << 12) + n0;
    for (int idx = t; idx < 2048; idx += 256)
        q_all[idx >> 6][idx & 63] = Y[(g0 + (idx >> 6)) * 416 + QOFF + (idx & 63)];
    __syncthreads();

    const float asig = 1.f / (1.f + expf(-alpha[0]));
    const float inv_scale = 1.0f / (8.0f + 1e-6f);
    const int kk = lane & 31, half = lane >> 5;

    for (int pp = 0; pp < 8; pp++) {
        const int n_l = (wid << 3) + pp;
        const size_t g = g0 + n_l;
        float part = 0.f;
        {
            const float* qr = &q_all[n_l][half << 5];
            const float* rkr = &rk_s[kk][half << 5];
#pragma unroll
            for (int j = 0; j < 32; j++) part += qr[j] * rkr[j];
        }
        part += __shfl_xor(part, 32);
        const float logit = part * inv_scale;
        float mx = logit;
#pragma unroll
        for (int off = 1; off < 32; off <<= 1) mx = fmaxf(mx, __shfl_xor(mx, off));
        const float e = expf(logit - mx);
        float s = e;
#pragma unroll
        for (int off = 1; off < 32; off <<= 1) s += __shfl_xor(s, off);
        const float w_own = e / s;

        float4 acc = make_float4(0.f, 0.f, 0.f, 0.f);
#pragma unroll
        for (int k2 = 0; k2 < 32; k2++) {
            const float w = __shfl(w_own, k2);
            const float4 rv = *(const float4*)&rv_s[k2][lane << 2];
            acc.x += w * rv.x; acc.y += w * rv.y;
            acc.z += w * rv.z; acc.w += w * rv.w;
        }
        float* spr = sp + g * 256 + (lane << 2);
        float4 spv = *(float4*)spr;
        float4 o;
        o.x = asig * acc.x + (1.f - asig) * spv.x;
        o.y = asig * acc.y + (1.f - asig) * spv.y;
        o.z = asig * acc.z + (1.f - asig) * spv.z;
        o.w = asig * acc.w + (1.f - asig) * spv.w;
        *(float4*)spr = o;
    }
}

// ============================================================================
// Kernel G: fused = fuse_w @ combined + fuse_b ; out = x + fused ; channel LN.
// ============================================================================
__global__ __launch_bounds__(256) void fuse_ln_kernel(
    const float* __restrict__ comb, const float* __restrict__ fuse_w,
    const float* __restrict__ fuse_b, const float* __restrict__ x,
    const float* __restrict__ ln_g, const float* __restrict__ ln_b,
    float* __restrict__ out)
{
    const int t = threadIdx.x;
    const int n0 = blockIdx.x << 5;
    const int b = blockIdx.y;

    __shared__ float smem[32 * 256 + 32 * 36];
    float (*Ws)[256] = (float (*)[256])smem;
    float (*cs)[36] = (float (*)[36])(smem + 32 * 256);
    float (*Fs)[260] = (float (*)[260])smem;
    __shared__ float red1[8][32], red2[8][32];
    __shared__ float mu_s[32], rs_s[32];

    const int og = t & 63;
    const int ng = t >> 6;
    float acc[4][8];
#pragma unroll
    for (int i = 0; i < 4; i++)
#pragma unroll
        for (int j = 0; j < 8; j++) acc[i][j] = 0.f;

    const int cl = (t << 2) & 31;
    const int nl = t >> 3;

    for (int c0 = 0; c0 < 256; c0 += 32) {
        __syncthreads();
        {
            const float* wr = fuse_w + (size_t)t * 256 + c0;
#pragma unroll
            for (int j = 0; j < 8; j++) {
                float4 w4 = *(const float4*)(wr + (j << 2));
                Ws[(j << 2) + 0][t] = w4.x;
                Ws[(j << 2) + 1][t] = w4.y;
                Ws[(j << 2) + 2][t] = w4.z;
                Ws[(j << 2) + 3][t] = w4.w;
            }
        }
        {
            float4 c4 = *(const float4*)(
                comb + ((size_t)(b * 4096 + n0 + nl)) * 256 + c0 + cl);
            cs[cl + 0][nl] = c4.x;
            cs[cl + 1][nl] = c4.y;
            cs[cl + 2][nl] = c4.z;
            cs[cl + 3][nl] = c4.w;
        }
        __syncthreads();
#pragma unroll
        for (int cc = 0; cc < 32; cc++) {
            float4 w4 = *(float4*)&Ws[cc][og << 2];
            float4 ca = *(float4*)&cs[cc][ng << 3];
            float4 cb = *(float4*)&cs[cc][(ng << 3) + 4];
            float wv[4] = {w4.x, w4.y, w4.z, w4.w};
            float cv[8] = {ca.x, ca.y, ca.z, ca.w, cb.x, cb.y, cb.z, cb.w};
#pragma unroll
            for (int i = 0; i < 4; i++)
#pragma unroll
                for (int j = 0; j < 8; j++) acc[i][j] += wv[i] * cv[j];
        }
    }

    __syncthreads();
#pragma unroll
    for (int i = 0; i < 4; i++) {
        const int o = (og << 2) + i;
        const float fb = fuse_b[o];
        const float* xr = x + ((size_t)(b * 256 + o)) * 4096 + n0 + (ng << 3);
        float4 xa = *(const float4*)xr;
        float4 xb = *(const float4*)(xr + 4);
        float xv[8] = {xa.x, xa.y, xa.z, xa.w, xb.x, xb.y, xb.z, xb.w};
#pragma unroll
        for (int j = 0; j < 8; j++)
            Fs[(ng << 3) + j][o] = acc[i][j] + fb + xv[j];
    }
    __syncthreads();
    {
        const int n = t & 31, part = t >> 5;
        float s1 = 0.f, s2 = 0.f;
#pragma unroll
        for (int i = 0; i < 32; i++) {
            const float v = Fs[n][(part << 5) + i];
            s1 += v; s2 += v * v;
        }
        red1[part][n] = s1; red2[part][n] = s2;
    }
    __syncthreads();
    if (t < 32) {
        float s1 = 0.f, s2 = 0.f;
#pragma unroll
        for (int p = 0; p < 8; p++) { s1 += red1[p][t]; s2 += red2[p][t]; }
        const float mean = s1 * (1.f / 256.f);
        const float var = s2 * (1.f / 256.f) - mean * mean;
        mu_s[t] = mean;
        rs_s[t] = rsqrtf(var + 1e-5f);
    }
    __syncthreads();
#pragma unroll
    for (int j = 0; j < 32; j++) {
        const int idx = (j << 8) + t;
        const int o = idx >> 5, n = idx & 31;
        const float v = (Fs[n][o] - mu_s[n]) * rs_s[n] * ln_g[o] + ln_b[o];
        out[((size_t)(b * 256 + o)) * 4096 + n0 + n] = v;
    }
}

// ============================================================================
extern "C" void kernel_launch(void* const* d_in, const int* in_sizes, int n_in,
                              void* d_out, int out_size, void* d_ws, size_t ws_size,
                              hipStream_t stream)
{
    const float* x = (const float*)d_in[0];
    const float* sem_w = (const float*)d_in[1];
    const float* sem_b = (const float*)d_in[2];
    const float* q_w = (const float*)d_in[3];
    const float* k_w = (const float*)d_in[4];
    const float* v_w = (const float*)d_in[5];
    const float* fuse_w = (const float*)d_in[6];
    const float* fuse_b = (const float*)d_in[7];
    const float* alpha = (const float*)d_in[8];
    const float* ln_g = (const float*)d_in[9];
    const float* ln_b = (const float*)d_in[10];
    float* out = (float*)d_out;

    char* ws = (char*)d_ws;
    float* Y    = (float*)(ws);              // 13,631,488 B
    float* SP   = (float*)(ws + 13631488);   //  8,388,608 B
    float* P    = (float*)(ws + 22020096);   //  2,621,440 B
    float* REG  = (float*)(ws + 24641536);   //     81,920 B
    int*   HR   = (int*)  (ws + 24723456);   //     32,768 B
    int*   TI   = (int*)  (ws + 24756224);   //     65,536 B
    int*   CNT  = (int*)  (ws + 24821760);   //        256 B
    int*   PLIST= (int*)  (ws + 24822016);   //  1,048,576 B -> total 25,870,592

    proj_kernel<<<dim3(64, 7, 2), 256, 0, stream>>>(x, sem_w, sem_b, q_w, k_w, v_w, Y);
    semsoft_kernel<<<32, 256, 0, stream>>>(Y, HR);
    hipMemsetAsync(CNT, 0, 256, stream);
    bin_kernel<<<32, 256, 0, stream>>>(HR, CNT, PLIST);
    region_partial_kernel<<<dim3(32, 2, 5), 256, 0, stream>>>(Y, P);
    region_reduce_kernel<<<80, 256, 0, stream>>>(P, REG);
    topk_sem_kernel<<<dim3(32, 2), 256, 0, stream>>>(Y, TI);
    sparse_attn_kernel<<<dim3(64, NSUB), 256, 0, stream>>>(Y, CNT, PLIST, TI, SP);
    combine_kernel<<<dim3(128, 2), 256, 0, stream>>>(Y, REG, alpha, SP);
    fuse_ln_kernel<<<dim3(128, 2), 256, 0, stream>>>(SP, fuse_w, fuse_b, x, ln_g, ln_b, out);
}